// Round 2
// baseline (387.584 us; speedup 1.0000x reference)
//
#include <hip/hip_runtime.h>
#include <hip/hip_bf16.h>

// LearnedPairConnect: B=4, N=512, D=48. Output dtype: FP32 (reference is all-fp32;
// round-1 failure signature proved harness reads d_out as float*).
// Reference: pair(i,j) = [x_i, x_j]; h1 = gelu(pair@W1+b1); h2 = gelu(h1@W2+b2);
// P = h2@W3+b3 (masked j>i); w = softmax_j(||P||); out[i] = sum_j w_j P_j.
// Trick: pair@W1 = (x@W1_top)[i] + (x@W1_bot)[j]  -> precompute U (with +b1) and V.
// Workspace: U,V fp32, 2 * 4*512*96 floats = 1.57 MB (written every launch).

constexpr int BATCH = 4;
constexpr int SEQ   = 512;
constexpr int DIM   = 48;   // D = D_OUT
constexpr int DIM2  = 96;   // 2*D
constexpr int CH    = 32;   // j-chunk per iteration
constexpr int SA_LD = 98;   // padded stride for 96-wide rows (bank-conflict break)
constexpr int SH_LD = 50;   // padded stride for 48-wide rows

__device__ __forceinline__ float gelu_exact(float x) {
    // jax.nn.gelu(approximate=False) = 0.5*x*(1+erf(x/sqrt(2)))
    return 0.5f * x * (1.0f + erff(x * 0.70710678118654752440f));
}

// ---------------- Kernel 1: U = x@W1[:48,:] + b1 ; V = x@W1[48:,:] ----------------
__global__ __launch_bounds__(192) void uv_kernel(
    const float* __restrict__ x, const float* __restrict__ W1,
    const float* __restrict__ b1, float* __restrict__ U, float* __restrict__ V)
{
    __shared__ float sx[DIM];
    const int row = blockIdx.x;          // b*SEQ + n
    const int t   = threadIdx.x;         // 192 threads: 96 for U, 96 for V
    if (t < DIM) sx[t] = x[row * DIM + t];
    __syncthreads();
    const bool isU = (t < DIM2);
    const int  k   = isU ? t : (t - DIM2);
    const float* Wcol = W1 + (isU ? 0 : DIM * DIM2);
    float acc = isU ? b1[k] : 0.0f;
    #pragma unroll 8
    for (int m = 0; m < DIM; ++m)
        acc = fmaf(sx[m], Wcol[m * DIM2 + k], acc);  // lanes: consecutive k -> coalesced
    float* dst = isU ? U : V;
    dst[row * DIM2 + k] = acc;
}

// ---------------- Kernel 2: fused pair-MLP + online softmax over j ----------------
__global__ __launch_bounds__(256) void pair_kernel(
    const float* __restrict__ U, const float* __restrict__ V,
    const float* __restrict__ W2, const float* __restrict__ b2,
    const float* __restrict__ W3, const float* __restrict__ b3,
    float* __restrict__ out)
{
    __shared__ float sW2[DIM2 * DIM];   // 18 KB
    __shared__ float sW3[DIM * DIM];    // 9 KB
    __shared__ float sb2[DIM];
    __shared__ float sb3[DIM];
    __shared__ float sUi[DIM2];
    __shared__ float sa[CH * SA_LD];    // layer-1 activations; aliased later as P
    __shared__ float sh[CH * SH_LD];    // layer-2 activations
    __shared__ float snrm[CH];
    __shared__ float se[CH];
    __shared__ float sacc[DIM];
    __shared__ float sml[2];            // running max, running sum
    __shared__ float sscale;
    // total ~47 KB -> 3 blocks/CU

    const int t   = threadIdx.x;
    const int bid = blockIdx.x;
    const int b   = bid & (BATCH - 1);
    const int i   = (SEQ - 1) - (bid >> 2);   // big-i blocks first (LPT balance)
    const int rowbase = b * SEQ + i;

    for (int idx = t; idx < DIM2 * DIM; idx += 256) sW2[idx] = W2[idx];
    for (int idx = t; idx < DIM * DIM;  idx += 256) sW3[idx] = W3[idx];
    if (t < DIM)  { sb2[t] = b2[t]; sb3[t] = b3[t]; sacc[t] = 0.0f; }
    if (t < DIM2) sUi[t] = U[rowbase * DIM2 + t];
    if (t == 0)   { sml[0] = -1e30f; sml[1] = 0.0f; }
    __syncthreads();

    const int jj = t >> 3;      // 0..31 : which pair in chunk
    const int cg = t & 7;       // 0..7  : output-column group
    const int c0 = cg * 6;      // 6 outputs per thread
    float* sP = sa;             // GEMM3 output, stride SH_LD (sa is dead by then)

    for (int j0 = 0; j0 <= i; j0 += CH) {
        const int JJ = min(CH, i + 1 - j0);

        // --- A: layer-1 preact + gelu. j0+aj <= 511 always, so out-of-range jj in
        //        tail chunks read valid V rows; excluded via se=0.
        for (int idx = t; idx < CH * DIM2; idx += 256) {
            int aj = idx / DIM2;
            int k  = idx - aj * DIM2;
            float v = sUi[k] + V[(b * SEQ + j0 + aj) * DIM2 + k];
            sa[aj * SA_LD + k] = gelu_exact(v);
        }
        __syncthreads();

        // --- GEMM2: h = gelu(a @ W2 + b2), each thread 1 jj x 6 cols, K=96
        {
            float a0 = sb2[c0+0], a1 = sb2[c0+1], a2 = sb2[c0+2];
            float a3 = sb2[c0+3], a4 = sb2[c0+4], a5 = sb2[c0+5];
            const float* aRow = &sa[jj * SA_LD];
            #pragma unroll 8
            for (int k = 0; k < DIM2; ++k) {
                float av = aRow[k];
                const float* w = &sW2[k * DIM + c0];
                a0 = fmaf(av, w[0], a0); a1 = fmaf(av, w[1], a1);
                a2 = fmaf(av, w[2], a2); a3 = fmaf(av, w[3], a3);
                a4 = fmaf(av, w[4], a4); a5 = fmaf(av, w[5], a5);
            }
            float* hRow = &sh[jj * SH_LD + c0];
            hRow[0] = gelu_exact(a0); hRow[1] = gelu_exact(a1);
            hRow[2] = gelu_exact(a2); hRow[3] = gelu_exact(a3);
            hRow[4] = gelu_exact(a4); hRow[5] = gelu_exact(a5);
        }
        __syncthreads();

        // --- GEMM3: P = h @ W3 + b3, K=48; fused squared-norm partials
        {
            float a0 = sb3[c0+0], a1 = sb3[c0+1], a2 = sb3[c0+2];
            float a3 = sb3[c0+3], a4 = sb3[c0+4], a5 = sb3[c0+5];
            const float* hRow = &sh[jj * SH_LD];
            #pragma unroll 8
            for (int c = 0; c < DIM; ++c) {
                float hv = hRow[c];
                const float* w = &sW3[c * DIM + c0];
                a0 = fmaf(hv, w[0], a0); a1 = fmaf(hv, w[1], a1);
                a2 = fmaf(hv, w[2], a2); a3 = fmaf(hv, w[3], a3);
                a4 = fmaf(hv, w[4], a4); a5 = fmaf(hv, w[5], a5);
            }
            float* pRow = &sP[jj * SH_LD + c0];
            pRow[0] = a0; pRow[1] = a1; pRow[2] = a2;
            pRow[3] = a3; pRow[4] = a4; pRow[5] = a5;
            float p = a0*a0 + a1*a1 + a2*a2 + a3*a3 + a4*a4 + a5*a5;
            p += __shfl_down(p, 4, 8);
            p += __shfl_down(p, 2, 8);
            p += __shfl_down(p, 1, 8);
            if (cg == 0) snrm[jj] = sqrtf(p);
        }
        __syncthreads();

        // --- online softmax update (wave 0 only)
        if (t < 64) {
            float nr = (t < JJ) ? snrm[t] : -1e30f;     // lanes 32..63 inert
            float mx = nr;
            mx = fmaxf(mx, __shfl_xor(mx, 16, 32));
            mx = fmaxf(mx, __shfl_xor(mx,  8, 32));
            mx = fmaxf(mx, __shfl_xor(mx,  4, 32));
            mx = fmaxf(mx, __shfl_xor(mx,  2, 32));
            mx = fmaxf(mx, __shfl_xor(mx,  1, 32));
            float mrun = sml[0];
            float newm = fmaxf(mrun, mx);
            float e = (t < JJ) ? expf(nr - newm) : 0.0f;
            if (t < 32) se[t] = e;
            float s = e;
            s += __shfl_xor(s, 16, 32);
            s += __shfl_xor(s,  8, 32);
            s += __shfl_xor(s,  4, 32);
            s += __shfl_xor(s,  2, 32);
            s += __shfl_xor(s,  1, 32);
            if (t == 0) {
                float sc = expf(mrun - newm);   // first chunk: exp(-1e30)=0, no NaN
                sscale = sc;
                sml[0] = newm;
                sml[1] = sml[1] * sc + s;
            }
        }
        __syncthreads();

        // --- accumulate weighted P into sacc (threads 0..47)
        if (t < DIM) {
            float a = sacc[t] * sscale;
            #pragma unroll 8
            for (int q = 0; q < CH; ++q)
                a = fmaf(se[q], sP[q * SH_LD + t], a);
            sacc[t] = a;
        }
        __syncthreads();  // protects sP (=sa) before next chunk's step A
    }

    if (t < DIM) {
        float o = sacc[t] / sml[1];
        out[rowbase * DIM + t] = o;
    }
}

extern "C" void kernel_launch(void* const* d_in, const int* in_sizes, int n_in,
                              void* d_out, int out_size, void* d_ws, size_t ws_size,
                              hipStream_t stream) {
    const float* x  = (const float*)d_in[0];
    const float* W1 = (const float*)d_in[1];
    const float* b1 = (const float*)d_in[2];
    const float* W2 = (const float*)d_in[3];
    const float* b2 = (const float*)d_in[4];
    const float* W3 = (const float*)d_in[5];
    const float* b3 = (const float*)d_in[6];
    float* out = (float*)d_out;

    float* U = (float*)d_ws;                       // [B*N, 96]
    float* V = U + BATCH * SEQ * DIM2;             // [B*N, 96]

    uv_kernel<<<BATCH * SEQ, 192, 0, stream>>>(x, W1, b1, U, V);
    pair_kernel<<<BATCH * SEQ, 256, 0, stream>>>(U, V, W2, b2, W3, b3, out);
}

// Round 3
// 154.488 us; speedup vs baseline: 2.5088x; 2.5088x over previous
//
#include <hip/hip_runtime.h>
#include <hip/hip_bf16.h>

// LearnedPairConnect: B=4, N=512, D=48. Output FP32.
// out[i] = sum_j softmax_j(||P_ij||) * P_ij, P = MLP3(concat(x_i,x_j)), j<=i.
// Layer 1 is linear in [x_i,x_j]: precompute U = x@W1_top + b1, V = x@W1_bot.
// Round-3 design: MFMA bf16 for GEMM2 (K=96) and GEMM3 (K=48, zero-padded to 64).
// Per block: one (b,i); chunks of 64 j; 4 waves, wave w = M-tile w (16 rows) x 3 N-tiles.

constexpr int BATCH = 4;
constexpr int SEQ   = 512;
constexpr int DIM   = 48;
constexpr int DIM2  = 96;
constexpr int CH    = 64;

constexpr int AW  = 104;  // sA / sW2T row stride (shorts): 16B-aligned rows, bank-spread
constexpr int HW  = 72;   // sH / sW3T row stride (shorts): 16B-aligned rows
constexpr int PW  = 50;   // sP row stride (floats)

typedef short short4v __attribute__((ext_vector_type(4)));
typedef short short8v __attribute__((ext_vector_type(8)));
typedef float float4v __attribute__((ext_vector_type(4)));

#define MFMA16(a, b, c) __builtin_amdgcn_mfma_f32_16x16x32_bf16(a, b, c, 0, 0, 0)

__device__ __forceinline__ float gelu_exact(float x) {
    return 0.5f * x * (1.0f + erff(x * 0.70710678118654752440f));
}
__device__ __forceinline__ short f2bf(float v) {
    __hip_bfloat16 h = __float2bfloat16(v);
    return *reinterpret_cast<short*>(&h);
}

// ---------------- Kernel 1: U = x@W1[:48,:] + b1 ; V = x@W1[48:,:] ----------------
// 8 rows per block: W1 column loads amortized 8x, 8-way ILP on the FMA chain.
__global__ __launch_bounds__(192) void uv_kernel(
    const float* __restrict__ x, const float* __restrict__ W1,
    const float* __restrict__ b1, float* __restrict__ U, float* __restrict__ V)
{
    __shared__ float sxT[DIM * 8];            // [m][r], r contiguous
    const int t = threadIdx.x;
    const int row0 = blockIdx.x * 8;
    for (int idx = t; idx < DIM * 8; idx += 192) {
        int r = idx / DIM, m = idx - r * DIM;
        sxT[m * 8 + r] = x[(row0 + r) * DIM + m];
    }
    __syncthreads();
    const bool isU = (t < DIM2);
    const int  k   = isU ? t : (t - DIM2);
    const float* Wcol = W1 + (isU ? 0 : DIM * DIM2) + k;
    float acc0, acc1, acc2, acc3, acc4, acc5, acc6, acc7;
    float binit = isU ? b1[k] : 0.0f;
    acc0 = acc1 = acc2 = acc3 = acc4 = acc5 = acc6 = acc7 = binit;
    #pragma unroll 8
    for (int m = 0; m < DIM; ++m) {
        float wv = Wcol[m * DIM2];
        const float4 xa = *(const float4*)&sxT[m * 8];
        const float4 xb = *(const float4*)&sxT[m * 8 + 4];
        acc0 = fmaf(wv, xa.x, acc0); acc1 = fmaf(wv, xa.y, acc1);
        acc2 = fmaf(wv, xa.z, acc2); acc3 = fmaf(wv, xa.w, acc3);
        acc4 = fmaf(wv, xb.x, acc4); acc5 = fmaf(wv, xb.y, acc5);
        acc6 = fmaf(wv, xb.z, acc6); acc7 = fmaf(wv, xb.w, acc7);
    }
    float* dst = isU ? U : V;
    dst[(row0 + 0) * DIM2 + k] = acc0; dst[(row0 + 1) * DIM2 + k] = acc1;
    dst[(row0 + 2) * DIM2 + k] = acc2; dst[(row0 + 3) * DIM2 + k] = acc3;
    dst[(row0 + 4) * DIM2 + k] = acc4; dst[(row0 + 5) * DIM2 + k] = acc5;
    dst[(row0 + 6) * DIM2 + k] = acc6; dst[(row0 + 7) * DIM2 + k] = acc7;
}

// ---------------- Kernel 2: MFMA pair-MLP + online softmax ----------------
__global__ __launch_bounds__(256) void pair_kernel(
    const float* __restrict__ U, const float* __restrict__ V,
    const float* __restrict__ W2, const float* __restrict__ b2,
    const float* __restrict__ W3, const float* __restrict__ b3,
    float* __restrict__ out)
{
    __shared__ short sA[CH * AW];        // 13312 B  layer-1 act, bf16, row=j, k contig
    __shared__ short sW2T[DIM * AW];     //  9984 B  W2^T: row=n, k contig (96)
    __shared__ short sH[CH * HW];        //  9216 B  layer-2 act bf16, k padded 48->64 w/ zeros
    __shared__ short sW3T[DIM * HW];     //  6912 B  W3^T: row=n, k 0..47 + zeros 48..63
    __shared__ float sP[CH * PW];        // 12800 B  GEMM3 out fp32
    __shared__ float sUi[DIM2];
    __shared__ float sB2f[DIM], sB3f[DIM];
    __shared__ float sNrm[CH], sE[CH];
    __shared__ float sMl[2];
    __shared__ float sScale;
    // total ~52.4 KB -> 3 blocks/CU

    const int t   = threadIdx.x;
    const int bid = blockIdx.x;
    const int b   = bid & (BATCH - 1);
    const int i   = (SEQ - 1) - (bid >> 2);   // LPT: big rows first
    const int rowbase = b * SEQ + i;

    // ---- one-time staging ----
    for (int idx = t; idx < DIM2 * DIM; idx += 256) {       // W2 [96][48] -> sW2T[n][k]
        int k = idx / DIM, n = idx - k * DIM;
        sW2T[n * AW + k] = f2bf(W2[idx]);
    }
    for (int idx = t; idx < DIM * DIM; idx += 256) {        // W3 [48][48] -> sW3T[n][k]
        int k = idx / DIM, n = idx - k * DIM;
        sW3T[n * HW + k] = f2bf(W3[idx]);
    }
    for (int idx = t; idx < DIM * 16; idx += 256) {         // zero-pad W3T k=48..63
        int n = idx >> 4;
        sW3T[n * HW + 48 + (idx & 15)] = 0;
    }
    for (int idx = t; idx < CH * 16; idx += 256) {          // zero-pad H k=48..63
        int r = idx >> 4;
        sH[r * HW + 48 + (idx & 15)] = 0;
    }
    if (t < DIM2) sUi[t] = U[rowbase * DIM2 + t];
    if (t < DIM)  { sB2f[t] = b2[t]; sB3f[t] = b3[t]; }
    if (t == 0)   { sMl[0] = -1e30f; sMl[1] = 0.0f; }
    __syncthreads();

    const int lane = t & 63;
    const int w    = t >> 6;           // wave id = M-tile
    const int col  = lane & 15;        // MFMA col / B-frag n-within-tile
    const int quad = lane >> 4;        // k-chunk selector (A/B), row group (C)
    const int qo   = quad * 8;
    const int m4   = w * 16 + col;     // A-frag row
    const int hrow = w * 16 + quad * 4;

    float regAcc = 0.0f;               // per-lane output partial: wave w, col=lane
    const int cc = (lane < DIM) ? lane : (DIM - 1);

    for (int j0 = 0; j0 <= i; j0 += CH) {
        const int JJ = min(CH, i + 1 - j0);

        // ---- A-pack: A = gelu(U_i + V_j) -> bf16 LDS, rows j0..j0+63 (always valid mem)
        {
            const float* Vb = V + (b * SEQ + j0) * DIM2;
            #pragma unroll
            for (int it = 0; it < 6; ++it) {
                int f   = t + it * 256;       // 0..1535 float4s
                int row = f / 24;
                int kq  = f - row * 24;
                const float4 vv = *(const float4*)(Vb + row * DIM2 + kq * 4);
                const float4 uu = *(const float4*)&sUi[kq * 4];
                short4v o;
                o[0] = f2bf(gelu_exact(uu.x + vv.x));
                o[1] = f2bf(gelu_exact(uu.y + vv.y));
                o[2] = f2bf(gelu_exact(uu.z + vv.z));
                o[3] = f2bf(gelu_exact(uu.w + vv.w));
                *(short4v*)&sA[row * AW + kq * 4] = o;
            }
        }
        __syncthreads();   // B1: A ready

        // ---- GEMM2: H = gelu(A @ W2 + b2), K=96 (3 MFMA steps), 3 N-tiles
        {
            const short* arow = &sA[m4 * AW + qo];
            short8v a0 = *(const short8v*)(arow + 0);
            short8v a1 = *(const short8v*)(arow + 32);
            short8v a2 = *(const short8v*)(arow + 64);
            float4v c0 = {0.f, 0.f, 0.f, 0.f}, c1 = c0, c2 = c0;
            const short* w2b = &sW2T[col * AW + qo];
            c0 = MFMA16(a0, *(const short8v*)(w2b + 0),            c0);
            c0 = MFMA16(a1, *(const short8v*)(w2b + 32),           c0);
            c0 = MFMA16(a2, *(const short8v*)(w2b + 64),           c0);
            c1 = MFMA16(a0, *(const short8v*)(w2b + 16*AW + 0),    c1);
            c1 = MFMA16(a1, *(const short8v*)(w2b + 16*AW + 32),   c1);
            c1 = MFMA16(a2, *(const short8v*)(w2b + 16*AW + 64),   c1);
            c2 = MFMA16(a0, *(const short8v*)(w2b + 32*AW + 0),    c2);
            c2 = MFMA16(a1, *(const short8v*)(w2b + 32*AW + 32),   c2);
            c2 = MFMA16(a2, *(const short8v*)(w2b + 32*AW + 64),   c2);
            // epilogue: bias + gelu in-register, scatter bf16 to sH (C-layout rows)
            float bb0 = sB2f[col], bb1 = sB2f[16 + col], bb2 = sB2f[32 + col];
            #pragma unroll
            for (int r = 0; r < 4; ++r) {
                sH[(hrow + r) * HW +  0 + col] = f2bf(gelu_exact(c0[r] + bb0));
                sH[(hrow + r) * HW + 16 + col] = f2bf(gelu_exact(c1[r] + bb1));
                sH[(hrow + r) * HW + 32 + col] = f2bf(gelu_exact(c2[r] + bb2));
            }
        }
        __syncthreads();   // B2: H ready

        // ---- GEMM3: P = H @ W3 + b3, K=64 (48 + zero pad), + in-register row norms
        {
            const short* hrw = &sH[m4 * HW + qo];
            short8v a0 = *(const short8v*)(hrw + 0);
            short8v a1 = *(const short8v*)(hrw + 32);
            float4v c0 = {0.f, 0.f, 0.f, 0.f}, c1 = c0, c2 = c0;
            const short* w3b = &sW3T[col * HW + qo];
            c0 = MFMA16(a0, *(const short8v*)(w3b + 0),          c0);
            c0 = MFMA16(a1, *(const short8v*)(w3b + 32),         c0);
            c1 = MFMA16(a0, *(const short8v*)(w3b + 16*HW + 0),  c1);
            c1 = MFMA16(a1, *(const short8v*)(w3b + 16*HW + 32), c1);
            c2 = MFMA16(a0, *(const short8v*)(w3b + 32*HW + 0),  c2);
            c2 = MFMA16(a1, *(const short8v*)(w3b + 32*HW + 32), c2);
            float bb0 = sB3f[col], bb1 = sB3f[16 + col], bb2 = sB3f[32 + col];
            #pragma unroll
            for (int r = 0; r < 4; ++r) {
                float v0 = c0[r] + bb0, v1 = c1[r] + bb1, v2 = c2[r] + bb2;
                float* prow = &sP[(hrow + r) * PW];
                prow[ 0 + col] = v0; prow[16 + col] = v1; prow[32 + col] = v2;
                float ss = v0 * v0 + v1 * v1 + v2 * v2;   // row-norm partial (this col)
                ss += __shfl_xor(ss, 1);                  // reduce over 16 cols (in quad)
                ss += __shfl_xor(ss, 2);
                ss += __shfl_xor(ss, 4);
                ss += __shfl_xor(ss, 8);
                if (col == 0) sNrm[hrow + r] = sqrtf(ss);
            }
        }
        __syncthreads();   // B3: P + norms ready

        // ---- online softmax over this chunk's 64 norms (wave 0)
        if (t < 64) {
            float nr = (t < JJ) ? sNrm[t] : -1e30f;
            float mx = nr;
            mx = fmaxf(mx, __shfl_xor(mx, 1));  mx = fmaxf(mx, __shfl_xor(mx, 2));
            mx = fmaxf(mx, __shfl_xor(mx, 4));  mx = fmaxf(mx, __shfl_xor(mx, 8));
            mx = fmaxf(mx, __shfl_xor(mx, 16)); mx = fmaxf(mx, __shfl_xor(mx, 32));
            float mrun = sMl[0];
            float newm = fmaxf(mrun, mx);
            float e = (t < JJ) ? expf(nr - newm) : 0.0f;
            sE[t] = e;
            float s = e;
            s += __shfl_xor(s, 1);  s += __shfl_xor(s, 2);
            s += __shfl_xor(s, 4);  s += __shfl_xor(s, 8);
            s += __shfl_xor(s, 16); s += __shfl_xor(s, 32);
            if (t == 0) {
                float sc = expf(mrun - newm);    // 0 on first chunk
                sScale = sc;
                sMl[0] = newm;
                sMl[1] = sMl[1] * sc + s;
            }
        }
        __syncthreads();   // B4: sE/sScale ready

        // ---- weighted accumulate: wave w handles its own 16 rows, col=lane
        {
            float sc = sScale;
            float a = regAcc * sc;
            #pragma unroll
            for (int r = 0; r < 16; ++r)
                a = fmaf(sE[w * 16 + r], sP[(w * 16 + r) * PW + cc], a);
            regAcc = a;
        }
        // no barrier: next A-pack touches only sA; sP rewritten after next B2
    }

    __syncthreads();
    if (lane < DIM) sP[w * DIM + lane] = regAcc;   // 4 partials, reuse sP
    __syncthreads();
    if (t < DIM) {
        float o = (sP[t] + sP[DIM + t] + sP[2 * DIM + t] + sP[3 * DIM + t]) / sMl[1];
        out[rowbase * DIM + t] = o;
    }
}

extern "C" void kernel_launch(void* const* d_in, const int* in_sizes, int n_in,
                              void* d_out, int out_size, void* d_ws, size_t ws_size,
                              hipStream_t stream) {
    const float* x  = (const float*)d_in[0];
    const float* W1 = (const float*)d_in[1];
    const float* b1 = (const float*)d_in[2];
    const float* W2 = (const float*)d_in[3];
    const float* b2 = (const float*)d_in[4];
    const float* W3 = (const float*)d_in[5];
    const float* b3 = (const float*)d_in[6];
    float* out = (float*)d_out;

    float* U = (float*)d_ws;                       // [B*N, 96]
    float* V = U + BATCH * SEQ * DIM2;             // [B*N, 96]

    uv_kernel<<<BATCH * SEQ / 8, 192, 0, stream>>>(x, W1, b1, U, V);
    pair_kernel<<<BATCH * SEQ, 256, 0, stream>>>(U, V, W2, b2, W3, b3, out);
}

// Round 4
// 128.694 us; speedup vs baseline: 3.0117x; 1.2004x over previous
//
#include <hip/hip_runtime.h>
#include <hip/hip_bf16.h>

// LearnedPairConnect: B=4, N=512, D=48. Output FP32.
// out[i] = sum_j softmax_j(||P_ij||) * P_ij, P = MLP3(concat(x_i,x_j)), j<=i.
// Layer 1 linear split: U = x@W1_top + b1, V = x@W1_bot (uv_kernel).
// pair_kernel: MFMA bf16 GEMM2/GEMM3, P kept in C-registers (no sP LDS),
// per-wave redundant online softmax (wave-private m/l), A&S-7.1.26 fast gelu.
// LDS 40448 B -> 4 blocks/CU with __launch_bounds__(256,4).

constexpr int BATCH = 4;
constexpr int SEQ   = 512;
constexpr int DIM   = 48;
constexpr int DIM2  = 96;
constexpr int CH    = 64;

constexpr int AW  = 104;  // sA / sW2T row stride (shorts): 16B-aligned, 2-way-max banks
constexpr int HW  = 72;   // sH / sW3T row stride (shorts)

typedef short short4v __attribute__((ext_vector_type(4)));
typedef short short8v __attribute__((ext_vector_type(8)));
typedef float float4v __attribute__((ext_vector_type(4)));

#define MFMA16(a, b, c) __builtin_amdgcn_mfma_f32_16x16x32_bf16(a, b, c, 0, 0, 0)

// Fast exact-gelu: erf via Abramowitz-Stegun 7.1.26 (|eps| <= 1.5e-7).
// Verified: coeffs sum to 1.0 (erf(0)=0), erf(0.7071)=0.6827.
__device__ __forceinline__ float gelu_fast(float x) {
    float z  = fabsf(x) * 0.70710678118654752f;
    float t  = __builtin_amdgcn_rcpf(fmaf(0.3275911f, z, 1.0f));
    float p  =             1.061405429f;
    p = fmaf(p, t, -1.453152027f);
    p = fmaf(p, t,  1.421413741f);
    p = fmaf(p, t, -0.284496736f);
    p = fmaf(p, t,  0.254829592f);
    p = p * t;
    float e  = __builtin_amdgcn_exp2f(z * z * -1.4426950408889634f);
    float er = fmaf(-p, e, 1.0f);            // erf(|x|/sqrt2)
    er = copysignf(er, x);
    float hx = 0.5f * x;
    return fmaf(hx, er, hx);
}
__device__ __forceinline__ short f2bf(float v) {   // RNE f32->bf16, finite inputs
    unsigned u = __float_as_uint(v);
    u += 0x7FFFu + ((u >> 16) & 1u);
    return (short)(u >> 16);
}
constexpr float LOG2E = 1.4426950408889634f;

// ---------------- Kernel 1: U = x@W1[:48,:] + b1 ; V = x@W1[48:,:] ----------------
__global__ __launch_bounds__(192) void uv_kernel(
    const float* __restrict__ x, const float* __restrict__ W1,
    const float* __restrict__ b1, float* __restrict__ U, float* __restrict__ V)
{
    __shared__ float sxT[DIM * 4];            // [m][r]
    const int t = threadIdx.x;
    const int row0 = blockIdx.x * 4;
    if (t < DIM * 4) {
        int r = t / DIM, m = t - r * DIM;
        sxT[m * 4 + r] = x[(row0 + r) * DIM + m];
    }
    __syncthreads();
    const bool isU = (t < DIM2);
    const int  k   = isU ? t : (t - DIM2);
    const float* Wcol = W1 + (isU ? 0 : DIM * DIM2) + k;
    float binit = isU ? b1[k] : 0.0f;
    float a0 = binit, a1 = binit, a2 = binit, a3 = binit;
    #pragma unroll 8
    for (int m = 0; m < DIM; ++m) {
        float wv = Wcol[m * DIM2];
        const float4 xa = *(const float4*)&sxT[m * 4];
        a0 = fmaf(wv, xa.x, a0); a1 = fmaf(wv, xa.y, a1);
        a2 = fmaf(wv, xa.z, a2); a3 = fmaf(wv, xa.w, a3);
    }
    float* dst = isU ? U : V;
    dst[(row0 + 0) * DIM2 + k] = a0; dst[(row0 + 1) * DIM2 + k] = a1;
    dst[(row0 + 2) * DIM2 + k] = a2; dst[(row0 + 3) * DIM2 + k] = a3;
}

// ---------------- Kernel 2: MFMA pair-MLP, register-P, per-wave softmax ----------------
__global__ __launch_bounds__(256, 4) void pair_kernel(
    const float* __restrict__ U, const float* __restrict__ V,
    const float* __restrict__ W2, const float* __restrict__ b2,
    const float* __restrict__ W3, const float* __restrict__ b3,
    float* __restrict__ out)
{
    __shared__ __align__(16) short sA[CH * AW];     // 13312 B
    __shared__ __align__(16) short sW2T[DIM * AW];  //  9984 B
    __shared__ __align__(16) short sH[CH * HW];     //  9216 B
    __shared__ __align__(16) short sW3T[DIM * HW];  //  6912 B
    __shared__ __align__(16) float sUi[DIM2];       //   384 B
    __shared__ __align__(16) float sB2f[DIM];       //   192 B
    __shared__ __align__(16) float sB3f[DIM];       //   192 B
    __shared__ __align__(16) float sNrm[CH];        //   256 B
    // total 40448 B -> 4 blocks/CU

    const int t   = threadIdx.x;
    const int bid = blockIdx.x;
    const int b   = bid & (BATCH - 1);
    const int i   = (SEQ - 1) - (bid >> 2);   // LPT: big rows first
    const int rowbase = b * SEQ + i;

    // ---- one-time staging ----
    for (int idx = t; idx < DIM2 * DIM; idx += 256) {       // W2 [96][48] -> sW2T[n][k]
        int k = idx / DIM, n = idx - k * DIM;
        sW2T[n * AW + k] = f2bf(W2[idx]);
    }
    for (int idx = t; idx < DIM * DIM; idx += 256) {        // W3 [48][48] -> sW3T[n][k]
        int k = idx / DIM, n = idx - k * DIM;
        sW3T[n * HW + k] = f2bf(W3[idx]);
    }
    for (int idx = t; idx < DIM * 16; idx += 256)           // zero-pad W3T k=48..63
        sW3T[(idx >> 4) * HW + 48 + (idx & 15)] = 0;
    for (int idx = t; idx < CH * 16; idx += 256)            // zero-pad H k=48..63
        sH[(idx >> 4) * HW + 48 + (idx & 15)] = 0;
    if (t < DIM2) sUi[t] = U[rowbase * DIM2 + t];
    if (t < DIM)  { sB2f[t] = b2[t]; sB3f[t] = b3[t]; }
    __syncthreads();

    const int lane = t & 63;
    const int w    = t >> 6;           // wave id = M-tile
    const int col  = lane & 15;
    const int quad = lane >> 4;
    const int qo   = quad * 8;
    const int m4   = w * 16 + col;     // A-frag row
    const int rbase = w * 16 + quad * 4;  // C-frag row base

    // A-pack geometry (div-free): 4 threads per row, 6 float4 each
    const int pr = t >> 2;             // row 0..63
    const int pq = t & 3;
    float4 uu[6];
    #pragma unroll
    for (int k = 0; k < 6; ++k) uu[k] = *(const float4*)&sUi[(pq + 4 * k) * 4];

    float acc0 = 0.f, acc1 = 0.f, acc2 = 0.f;   // output partials (cols col,16+col,32+col)
    float m_run = -1e30f, l_run = 0.0f;          // wave-private (lane-replicated)

    for (int j0 = 0; j0 <= i; j0 += CH) {
        const int JJ = min(CH, i + 1 - j0);

        // ---- A-pack: A = gelu(U_i + V_j) -> bf16 LDS (rows j0..j0+63 are valid mem)
        {
            const float* Vb = V + (b * SEQ + j0 + pr) * DIM2 + pq * 4;
            #pragma unroll
            for (int k = 0; k < 6; ++k) {
                const float4 vv = *(const float4*)(Vb + 16 * k);
                short4v o;
                o[0] = f2bf(gelu_fast(uu[k].x + vv.x));
                o[1] = f2bf(gelu_fast(uu[k].y + vv.y));
                o[2] = f2bf(gelu_fast(uu[k].z + vv.z));
                o[3] = f2bf(gelu_fast(uu[k].w + vv.w));
                *(short4v*)&sA[pr * AW + (pq + 4 * k) * 4] = o;
            }
        }
        __syncthreads();   // B1: A ready

        // ---- GEMM2: H = gelu(A @ W2 + b2), K=96, 3 N-tiles
        {
            const short* arow = &sA[m4 * AW + qo];
            short8v a0 = *(const short8v*)(arow + 0);
            short8v a1 = *(const short8v*)(arow + 32);
            short8v a2 = *(const short8v*)(arow + 64);
            float4v c0 = {0.f,0.f,0.f,0.f}, c1 = c0, c2 = c0;
            const short* w2b = &sW2T[col * AW + qo];
            c0 = MFMA16(a0, *(const short8v*)(w2b + 0),          c0);
            c0 = MFMA16(a1, *(const short8v*)(w2b + 32),         c0);
            c0 = MFMA16(a2, *(const short8v*)(w2b + 64),         c0);
            c1 = MFMA16(a0, *(const short8v*)(w2b + 16*AW + 0),  c1);
            c1 = MFMA16(a1, *(const short8v*)(w2b + 16*AW + 32), c1);
            c1 = MFMA16(a2, *(const short8v*)(w2b + 16*AW + 64), c1);
            c2 = MFMA16(a0, *(const short8v*)(w2b + 32*AW + 0),  c2);
            c2 = MFMA16(a1, *(const short8v*)(w2b + 32*AW + 32), c2);
            c2 = MFMA16(a2, *(const short8v*)(w2b + 32*AW + 64), c2);
            float bb0 = sB2f[col], bb1 = sB2f[16 + col], bb2 = sB2f[32 + col];
            #pragma unroll
            for (int r = 0; r < 4; ++r) {
                sH[(rbase + r) * HW +  0 + col] = f2bf(gelu_fast(c0[r] + bb0));
                sH[(rbase + r) * HW + 16 + col] = f2bf(gelu_fast(c1[r] + bb1));
                sH[(rbase + r) * HW + 32 + col] = f2bf(gelu_fast(c2[r] + bb2));
            }
        }
        __syncthreads();   // B2: H ready

        // ---- GEMM3: P = H @ W3 + b3 (K=64 zero-padded), P stays in registers
        float4v p0, p1, p2;
        {
            const short* hrw = &sH[m4 * HW + qo];
            short8v a0 = *(const short8v*)(hrw + 0);
            short8v a1 = *(const short8v*)(hrw + 32);
            float4v c0 = {0.f,0.f,0.f,0.f}, c1 = c0, c2 = c0;
            const short* w3b = &sW3T[col * HW + qo];
            c0 = MFMA16(a0, *(const short8v*)(w3b + 0),          c0);
            c0 = MFMA16(a1, *(const short8v*)(w3b + 32),         c0);
            c1 = MFMA16(a0, *(const short8v*)(w3b + 16*HW + 0),  c1);
            c1 = MFMA16(a1, *(const short8v*)(w3b + 16*HW + 32), c1);
            c2 = MFMA16(a0, *(const short8v*)(w3b + 32*HW + 0),  c2);
            c2 = MFMA16(a1, *(const short8v*)(w3b + 32*HW + 32), c2);
            float bb0 = sB3f[col], bb1 = sB3f[16 + col], bb2 = sB3f[32 + col];
            #pragma unroll
            for (int r = 0; r < 4; ++r) {
                p0[r] = c0[r] + bb0; p1[r] = c1[r] + bb1; p2[r] = c2[r] + bb2;
                float ss = p0[r]*p0[r] + p1[r]*p1[r] + p2[r]*p2[r];
                ss += __shfl_xor(ss, 1);
                ss += __shfl_xor(ss, 2);
                ss += __shfl_xor(ss, 4);
                ss += __shfl_xor(ss, 8);
                if (col == 0) sNrm[rbase + r] = sqrtf(ss);
            }
        }
        __syncthreads();   // B3: sNrm ready

        // ---- redundant per-wave online softmax (identical across waves)
        {
            float nr = (lane < JJ) ? sNrm[lane] : -1e30f;
            float mx = nr;
            mx = fmaxf(mx, __shfl_xor(mx, 1));  mx = fmaxf(mx, __shfl_xor(mx, 2));
            mx = fmaxf(mx, __shfl_xor(mx, 4));  mx = fmaxf(mx, __shfl_xor(mx, 8));
            mx = fmaxf(mx, __shfl_xor(mx, 16)); mx = fmaxf(mx, __shfl_xor(mx, 32));
            float newm = fmaxf(m_run, mx);
            float e = (lane < JJ) ? __builtin_amdgcn_exp2f((nr - newm) * LOG2E) : 0.0f;
            float s = e;
            s += __shfl_xor(s, 1);  s += __shfl_xor(s, 2);
            s += __shfl_xor(s, 4);  s += __shfl_xor(s, 8);
            s += __shfl_xor(s, 16); s += __shfl_xor(s, 32);
            float sc = __builtin_amdgcn_exp2f((m_run - newm) * LOG2E);  // 0 on first chunk
            l_run = fmaf(l_run, sc, s);
            m_run = newm;
            acc0 *= sc; acc1 *= sc; acc2 *= sc;
            #pragma unroll
            for (int r = 0; r < 4; ++r) {
                float er = __shfl(e, rbase + r);   // e for this C-frag row
                acc0 = fmaf(er, p0[r], acc0);
                acc1 = fmaf(er, p1[r], acc1);
                acc2 = fmaf(er, p2[r], acc2);
            }
        }
        // no barrier: next writes (sA after B1-arrival ordering) are two barriers away
    }

    // ---- reduce acc over quads (rows) within wave, then across waves via LDS
    acc0 += __shfl_xor(acc0, 16); acc0 += __shfl_xor(acc0, 32);
    acc1 += __shfl_xor(acc1, 16); acc1 += __shfl_xor(acc1, 32);
    acc2 += __shfl_xor(acc2, 16); acc2 += __shfl_xor(acc2, 32);
    float* sRed = (float*)sA;     // sA dead after loop
    __syncthreads();              // all waves past final sA reads
    if (lane < 16) {
        sRed[w * DIM + lane]      = acc0;
        sRed[w * DIM + 16 + lane] = acc1;
        sRed[w * DIM + 32 + lane] = acc2;
    }
    __syncthreads();
    if (t < DIM) {
        float o = (sRed[t] + sRed[DIM + t] + sRed[2*DIM + t] + sRed[3*DIM + t]) / l_run;
        out[rowbase * DIM + t] = o;
    }
}

extern "C" void kernel_launch(void* const* d_in, const int* in_sizes, int n_in,
                              void* d_out, int out_size, void* d_ws, size_t ws_size,
                              hipStream_t stream) {
    const float* x  = (const float*)d_in[0];
    const float* W1 = (const float*)d_in[1];
    const float* b1 = (const float*)d_in[2];
    const float* W2 = (const float*)d_in[3];
    const float* b2 = (const float*)d_in[4];
    const float* W3 = (const float*)d_in[5];
    const float* b3 = (const float*)d_in[6];
    float* out = (float*)d_out;

    float* U = (float*)d_ws;                       // [B*N, 96]
    float* V = U + BATCH * SEQ * DIM2;             // [B*N, 96]

    uv_kernel<<<BATCH * SEQ / 4, 192, 0, stream>>>(x, W1, b1, U, V);
    pair_kernel<<<BATCH * SEQ, 256, 0, stream>>>(U, V, W2, b2, W3, b3, out);
}

// Round 5
// 114.888 us; speedup vs baseline: 3.3736x; 1.1202x over previous
//
#include <hip/hip_runtime.h>
#include <hip/hip_bf16.h>

// LearnedPairConnect: B=4, N=512, D=48. Output FP32.
// out[i] = sum_j softmax_j(||P_ij||) * P_ij, P = MLP3(concat(x_i,x_j)), j<=i.
// Layer-1 linear split: U = x@W1_top + b1, V = x@W1_bot (uv_kernel).
// pair_kernel R5: W2T/W3T MFMA B-frags + biases hoisted to registers (loop-invariant),
// LDS regions reused (23.2 KB), 7-instr tanh-gelu, v_perm bf16 pair-packing.

constexpr int BATCH = 4;
constexpr int SEQ   = 512;
constexpr int DIM   = 48;
constexpr int DIM2  = 96;
constexpr int CH    = 64;

constexpr int AW  = 104;  // sA row stride (shorts): 16B-aligned rows, bank-spread
constexpr int HW  = 72;   // sH row stride (shorts): 16B-aligned rows

typedef short short8v __attribute__((ext_vector_type(8)));
typedef float float4v __attribute__((ext_vector_type(4)));
typedef unsigned int uint2v __attribute__((ext_vector_type(2)));

#define MFMA16(a, b, c) __builtin_amdgcn_mfma_f32_16x16x32_bf16(a, b, c, 0, 0, 0)

// Minimal tanh-gelu: gelu(x) = x * (1 - 1/(1 + 2^(x*(c1 + c2*x^2)))).
// c1 = 2*log2(e)*sqrt(2/pi), c2 = c1*0.044715. |err vs exact gelu| <= ~1.5e-4.
// 7 VALU instrs (2 transcendental). Saturates correctly for large |x|.
__device__ __forceinline__ float gelu_tanh(float x) {
    float u = x * x;
    float q = fmaf(0.10294537f, u, 2.3022077f);
    float e = __builtin_amdgcn_exp2f(x * q);
    float r = __builtin_amdgcn_rcpf(e + 1.0f);
    return fmaf(-x, r, x);
}
// bf16 round-half-up, single element (staging / epilogue scalar path)
__device__ __forceinline__ short f2bf1(float v) {
    return (short)((__float_as_uint(v) + 0x8000u) >> 16);
}
// pack two f32 -> (bf16(b)<<16)|bf16(a) via v_perm_b32 (1 instr after the biases)
__device__ __forceinline__ unsigned pack_bf16x2(float a, float b) {
    unsigned ua = __float_as_uint(a) + 0x8000u;
    unsigned ub = __float_as_uint(b) + 0x8000u;
    return __builtin_amdgcn_perm(ub, ua, 0x07060302u);
}
constexpr float LOG2E = 1.4426950408889634f;

// ---------------- Kernel 1: U = x@W1[:48,:] + b1 ; V = x@W1[48:,:] ----------------
__global__ __launch_bounds__(192) void uv_kernel(
    const float* __restrict__ x, const float* __restrict__ W1,
    const float* __restrict__ b1, float* __restrict__ U, float* __restrict__ V)
{
    __shared__ float sxT[DIM * 4];            // [m][r]
    const int t = threadIdx.x;
    const int row0 = blockIdx.x * 4;
    if (t < DIM * 4) {
        int r = t / DIM, m = t - r * DIM;
        sxT[m * 4 + r] = x[(row0 + r) * DIM + m];
    }
    __syncthreads();
    const bool isU = (t < DIM2);
    const int  k   = isU ? t : (t - DIM2);
    const float* Wcol = W1 + (isU ? 0 : DIM * DIM2) + k;
    float binit = isU ? b1[k] : 0.0f;
    float a0 = binit, a1 = binit, a2 = binit, a3 = binit;
    #pragma unroll 8
    for (int m = 0; m < DIM; ++m) {
        float wv = Wcol[m * DIM2];
        const float4 xa = *(const float4*)&sxT[m * 4];
        a0 = fmaf(wv, xa.x, a0); a1 = fmaf(wv, xa.y, a1);
        a2 = fmaf(wv, xa.z, a2); a3 = fmaf(wv, xa.w, a3);
    }
    float* dst = isU ? U : V;
    dst[(row0 + 0) * DIM2 + k] = a0; dst[(row0 + 1) * DIM2 + k] = a1;
    dst[(row0 + 2) * DIM2 + k] = a2; dst[(row0 + 3) * DIM2 + k] = a3;
}

// ---------------- Kernel 2: MFMA pair-MLP, register weights, per-wave softmax -------
__global__ __launch_bounds__(256, 4) void pair_kernel(
    const float* __restrict__ U, const float* __restrict__ V,
    const float* __restrict__ W2, const float* __restrict__ b2,
    const float* __restrict__ W3, const float* __restrict__ b3,
    float* __restrict__ out)
{
    // region1 (13312 B): W2T staging -> sA (per-chunk) -> final reduction
    // region2 ( 9216 B): W3T staging -> sH (per-chunk; k-pad 48..63 stays zero)
    __shared__ __align__(16) char smem[23168];
    short* sA   = (short*)smem;
    short* sH   = (short*)(smem + 13312);
    float* sUi  = (float*)(smem + 22528);   // 384 B
    float* sNrm = (float*)(smem + 22912);   // 256 B

    const int t   = threadIdx.x;
    const int bid = blockIdx.x;
    const int b   = bid & (BATCH - 1);
    const int i   = (SEQ - 1) - (bid >> 2);   // LPT: big rows first
    const int rowbase = b * SEQ + i;

    const int lane = t & 63;
    const int w    = t >> 6;              // wave id = M-tile
    const int col  = lane & 15;
    const int quad = lane >> 4;
    const int qo   = quad * 8;
    const int m4   = w * 16 + col;        // A-frag row
    const int rbase = w * 16 + quad * 4;  // C-frag row base

    // ---- stage W2^T / W3^T (bf16) into LDS once, to harvest register fragments ----
    for (int idx = t; idx < DIM2 * DIM; idx += 256) {       // W2 [96][48] -> sA[n][k]
        int k = idx / DIM, n = idx - k * DIM;
        sA[n * AW + k] = f2bf1(W2[idx]);
    }
    for (int idx = t; idx < DIM * DIM; idx += 256) {        // W3 [48][48] -> sH[n][k]
        int k = idx / DIM, n = idx - k * DIM;
        sH[n * HW + k] = f2bf1(W3[idx]);
    }
    for (int idx = t; idx < CH * 16; idx += 256)            // zero k=48..63, all 64 rows
        sH[(idx >> 4) * HW + 48 + (idx & 15)] = 0;
    if (t < DIM2) sUi[t] = U[rowbase * DIM2 + t];
    __syncthreads();

    // ---- loop-invariant register fragments (B-operands) + biases ----
    const short* w2b = sA + col * AW + qo;
    const short8v w200 = *(const short8v*)(w2b + 0);
    const short8v w201 = *(const short8v*)(w2b + 32);
    const short8v w202 = *(const short8v*)(w2b + 64);
    const short8v w210 = *(const short8v*)(w2b + 16*AW + 0);
    const short8v w211 = *(const short8v*)(w2b + 16*AW + 32);
    const short8v w212 = *(const short8v*)(w2b + 16*AW + 64);
    const short8v w220 = *(const short8v*)(w2b + 32*AW + 0);
    const short8v w221 = *(const short8v*)(w2b + 32*AW + 32);
    const short8v w222 = *(const short8v*)(w2b + 32*AW + 64);
    const short* w3b = sH + col * HW + qo;
    const short8v w300 = *(const short8v*)(w3b + 0);
    const short8v w301 = *(const short8v*)(w3b + 32);
    const short8v w310 = *(const short8v*)(w3b + 16*HW + 0);
    const short8v w311 = *(const short8v*)(w3b + 16*HW + 32);
    const short8v w320 = *(const short8v*)(w3b + 32*HW + 0);
    const short8v w321 = *(const short8v*)(w3b + 32*HW + 32);
    const float bb20 = b2[col], bb21 = b2[16 + col], bb22 = b2[32 + col];
    const float bb30 = b3[col], bb31 = b3[16 + col], bb32 = b3[32 + col];
    __syncthreads();   // frags harvested; regions now free for sA/sH use

    // A-pack geometry: 4 threads per row, 6 float4 each
    const int pr = t >> 2;             // row 0..63
    const int pq = t & 3;

    float acc0 = 0.f, acc1 = 0.f, acc2 = 0.f;   // output partials (cols col,16+col,32+col)
    float m_run = -1e30f, l_run = 0.0f;          // wave-private (lane-replicated)

    for (int j0 = 0; j0 <= i; j0 += CH) {
        const int JJ = min(CH, i + 1 - j0);

        // ---- A-pack: A = gelu(U_i + V_j) -> bf16 LDS (rows j0..j0+63 valid memory)
        {
            const float* Vb = V + (b * SEQ + j0 + pr) * DIM2 + pq * 4;
            #pragma unroll
            for (int kk = 0; kk < 6; ++kk) {
                const float4 vv = *(const float4*)(Vb + 16 * kk);
                const float4 uu = *(const float4*)&sUi[(pq + 4 * kk) * 4];
                float g0 = gelu_tanh(uu.x + vv.x);
                float g1 = gelu_tanh(uu.y + vv.y);
                float g2 = gelu_tanh(uu.z + vv.z);
                float g3 = gelu_tanh(uu.w + vv.w);
                uint2v o;
                o.x = pack_bf16x2(g0, g1);
                o.y = pack_bf16x2(g2, g3);
                *(uint2v*)&sA[pr * AW + (pq + 4 * kk) * 4] = o;
            }
        }
        __syncthreads();   // B1: A ready

        // ---- GEMM2: H = gelu(A @ W2 + b2), K=96, 3 N-tiles (reg B-frags)
        {
            const short* arow = &sA[m4 * AW + qo];
            short8v a0 = *(const short8v*)(arow + 0);
            short8v a1 = *(const short8v*)(arow + 32);
            short8v a2 = *(const short8v*)(arow + 64);
            float4v c0 = {0.f,0.f,0.f,0.f}, c1 = c0, c2 = c0;
            c0 = MFMA16(a0, w200, c0); c0 = MFMA16(a1, w201, c0); c0 = MFMA16(a2, w202, c0);
            c1 = MFMA16(a0, w210, c1); c1 = MFMA16(a1, w211, c1); c1 = MFMA16(a2, w212, c1);
            c2 = MFMA16(a0, w220, c2); c2 = MFMA16(a1, w221, c2); c2 = MFMA16(a2, w222, c2);
            #pragma unroll
            for (int r = 0; r < 4; ++r) {
                sH[(rbase + r) * HW +  0 + col] = f2bf1(gelu_tanh(c0[r] + bb20));
                sH[(rbase + r) * HW + 16 + col] = f2bf1(gelu_tanh(c1[r] + bb21));
                sH[(rbase + r) * HW + 32 + col] = f2bf1(gelu_tanh(c2[r] + bb22));
            }
        }
        __syncthreads();   // B2: H ready

        // ---- GEMM3: P = H @ W3 + b3 (K=64 zero-padded), P stays in registers
        float4v p0, p1, p2;
        {
            const short* hrw = &sH[m4 * HW + qo];
            short8v a0 = *(const short8v*)(hrw + 0);
            short8v a1 = *(const short8v*)(hrw + 32);
            float4v c0 = {0.f,0.f,0.f,0.f}, c1 = c0, c2 = c0;
            c0 = MFMA16(a0, w300, c0); c0 = MFMA16(a1, w301, c0);
            c1 = MFMA16(a0, w310, c1); c1 = MFMA16(a1, w311, c1);
            c2 = MFMA16(a0, w320, c2); c2 = MFMA16(a1, w321, c2);
            #pragma unroll
            for (int r = 0; r < 4; ++r) {
                p0[r] = c0[r] + bb30; p1[r] = c1[r] + bb31; p2[r] = c2[r] + bb32;
                float ss = p0[r]*p0[r] + p1[r]*p1[r] + p2[r]*p2[r];
                ss += __shfl_xor(ss, 1);
                ss += __shfl_xor(ss, 2);
                ss += __shfl_xor(ss, 4);
                ss += __shfl_xor(ss, 8);
                if (col == 0) sNrm[rbase + r] = sqrtf(ss);
            }
        }
        __syncthreads();   // B3: sNrm ready

        // ---- redundant per-wave online softmax (identical across waves)
        {
            float nr = (lane < JJ) ? sNrm[lane] : -1e30f;
            float mx = nr;
            mx = fmaxf(mx, __shfl_xor(mx, 1));  mx = fmaxf(mx, __shfl_xor(mx, 2));
            mx = fmaxf(mx, __shfl_xor(mx, 4));  mx = fmaxf(mx, __shfl_xor(mx, 8));
            mx = fmaxf(mx, __shfl_xor(mx, 16)); mx = fmaxf(mx, __shfl_xor(mx, 32));
            float newm = fmaxf(m_run, mx);
            float e = (lane < JJ) ? __builtin_amdgcn_exp2f((nr - newm) * LOG2E) : 0.0f;
            float s = e;
            s += __shfl_xor(s, 1);  s += __shfl_xor(s, 2);
            s += __shfl_xor(s, 4);  s += __shfl_xor(s, 8);
            s += __shfl_xor(s, 16); s += __shfl_xor(s, 32);
            float sc = __builtin_amdgcn_exp2f((m_run - newm) * LOG2E);  // 0 on first chunk
            l_run = fmaf(l_run, sc, s);
            m_run = newm;
            acc0 *= sc; acc1 *= sc; acc2 *= sc;
            #pragma unroll
            for (int r = 0; r < 4; ++r) {
                float er = __shfl(e, rbase + r);   // e for this C-frag row
                acc0 = fmaf(er, p0[r], acc0);
                acc1 = fmaf(er, p1[r], acc1);
                acc2 = fmaf(er, p2[r], acc2);
            }
        }
        // no barrier: next sA writes are one barrier (B1) away from these sNrm reads,
        // and sNrm is rewritten only after next B3.
    }

    // ---- reduce acc over quads (rows) within wave, then across waves via LDS
    acc0 += __shfl_xor(acc0, 16); acc0 += __shfl_xor(acc0, 32);
    acc1 += __shfl_xor(acc1, 16); acc1 += __shfl_xor(acc1, 32);
    acc2 += __shfl_xor(acc2, 16); acc2 += __shfl_xor(acc2, 32);
    float* sRed = (float*)sA;     // region1 dead after loop
    __syncthreads();              // all waves past final sA reads
    if (lane < 16) {
        sRed[w * DIM + lane]      = acc0;
        sRed[w * DIM + 16 + lane] = acc1;
        sRed[w * DIM + 32 + lane] = acc2;
    }
    __syncthreads();
    if (t < DIM) {
        float o = (sRed[t] + sRed[DIM + t] + sRed[2*DIM + t] + sRed[3*DIM + t]) / l_run;
        out[rowbase * DIM + t] = o;
    }
}

extern "C" void kernel_launch(void* const* d_in, const int* in_sizes, int n_in,
                              void* d_out, int out_size, void* d_ws, size_t ws_size,
                              hipStream_t stream) {
    const float* x  = (const float*)d_in[0];
    const float* W1 = (const float*)d_in[1];
    const float* b1 = (const float*)d_in[2];
    const float* W2 = (const float*)d_in[3];
    const float* b2 = (const float*)d_in[4];
    const float* W3 = (const float*)d_in[5];
    const float* b3 = (const float*)d_in[6];
    float* out = (float*)d_out;

    float* U = (float*)d_ws;                       // [B*N, 96]
    float* V = U + BATCH * SEQ * DIM2;             // [B*N, 96]

    uv_kernel<<<BATCH * SEQ / 4, 192, 0, stream>>>(x, W1, b1, U, V);
    pair_kernel<<<BATCH * SEQ, 256, 0, stream>>>(U, V, W2, b2, W3, b3, out);
}